// Round 9
// baseline (174.483 us; speedup 1.0000x reference)
//
#include <hip/hip_runtime.h>
#include <hip/hip_bf16.h>

#define IN_F   128
#define OUT_F  64
#define TSTRIDE 136   // LDS row stride in ushorts (16B-aligned: 272 B)

typedef __attribute__((ext_vector_type(8))) short short8;   // 8 bf16
typedef __attribute__((ext_vector_type(4))) float floatx4;  // MFMA accumulator

__device__ inline unsigned short f32_to_bf16_rne(float f) {
    unsigned int u = __float_as_uint(f);
    unsigned int r = (u + 0x7FFFu + ((u >> 16) & 1u)) >> 16;
    return (unsigned short)r;
}

// ---------------------------------------------------------------------------
// CSR build: count -> 3-phase scan -> fill (fill bumps offsets start->end).
// ---------------------------------------------------------------------------
__global__ __launch_bounds__(256) void count_edges(const int* __restrict__ edst,
                                                   int* __restrict__ counts,
                                                   int n_edges) {
    const int e = blockIdx.x * 256 + threadIdx.x;
    if (e < n_edges) atomicAdd(&counts[edst[e]], 1);
}

__global__ __launch_bounds__(256) void scan_blocks(const int* __restrict__ counts,
                                                   int* __restrict__ offsets,
                                                   int* __restrict__ blockTotals,
                                                   int n) {
    __shared__ int waveTot[4];
    const int tid = threadIdx.x;
    const int lane = tid & 63;
    const int wave = tid >> 6;
    const int i = blockIdx.x * 256 + tid;

    const int v = (i < n) ? counts[i] : 0;

    int s = v;
    #pragma unroll
    for (int off = 1; off < 64; off <<= 1) {
        const int t = __shfl_up(s, off, 64);
        if (lane >= off) s += t;
    }
    if (lane == 63) waveTot[wave] = s;
    __syncthreads();

    int base = 0;
    #pragma unroll
    for (int w = 0; w < 4; ++w)
        if (w < wave) base += waveTot[w];

    const int incl = s + base;
    if (i < n) offsets[i] = incl - v;
    if (tid == 255) blockTotals[blockIdx.x] = incl;
}

__global__ __launch_bounds__(256) void scan_totals(const int* __restrict__ blockTotals,
                                                   int* __restrict__ blockBases,
                                                   int nb) {
    __shared__ int part[256];
    const int t = threadIdx.x;
    const int v = (t < nb) ? blockTotals[t] : 0;
    part[t] = v;
    __syncthreads();
    for (int off = 1; off < 256; off <<= 1) {
        const int u = (t >= off) ? part[t - off] : 0;
        __syncthreads();
        part[t] += u;
        __syncthreads();
    }
    if (t < nb) blockBases[t] = part[t] - v;
}

__global__ __launch_bounds__(256) void add_base(int* __restrict__ offsets,
                                                const int* __restrict__ blockBases,
                                                int n) {
    const int i = blockIdx.x * 256 + threadIdx.x;
    if (i < n) offsets[i] += blockBases[blockIdx.x];
}

__global__ __launch_bounds__(256) void fill_edges(const int* __restrict__ esrc,
                                                  const int* __restrict__ edst,
                                                  int* __restrict__ offsets,
                                                  int* __restrict__ elist,
                                                  int n_edges) {
    const int e = blockIdx.x * 256 + threadIdx.x;
    if (e < n_edges) {
        const int d = edst[e];
        const int slot = atomicAdd(&offsets[d], 1);
        elist[slot] = esrc[e];
    }
}

// ---------------------------------------------------------------------------
// agg_gemm: the algebraic restructure. out = ((sum_e x[src_e] + x[d]) @ W)
// / (deg+1) + b. Block = 64 dsts, wave = 16 dsts.
// Phase 1: wave sequentially aggregates each of its 16 dst rows in f32
// registers (float2/lane; 512 B coalesced per edge-row read, 4-deep MLP),
// converts to bf16 into its PRIVATE LDS strip (no cross-wave sharing ->
// no barrier; same-wave lgkmcnt(0) fence only).
// Phase 2: 16x128 @ 128x64 via 16 MFMA (A from strip, B from Wt), fused
// /(deg+1)+b epilogue, f32 out store (64 B contiguous per 16-lane group).
// ---------------------------------------------------------------------------
__global__ __launch_bounds__(256) void agg_gemm(const float* __restrict__ x,
                                                const float* __restrict__ W,
                                                const int* __restrict__ offsets,
                                                const int* __restrict__ counts,
                                                const int* __restrict__ elist,
                                                const float* __restrict__ b,
                                                float* __restrict__ out,
                                                int n_dst) {
    __shared__ unsigned short Wt[64 * TSTRIDE];      // 17.4 KB  (W^T, bf16)
    __shared__ unsigned short ag[4][16 * TSTRIDE];   // 17.4 KB  (per-wave strips)

    const int tid = threadIdx.x;
    const int lane = tid & 63;
    const int wave = tid >> 6;

    // One-time: W (128x64 f32) -> Wt[col][k] bf16.
    #pragma unroll
    for (int i = 0; i < 32; ++i) {
        const int idx = tid + i * 256;          // 0..8191
        Wt[(idx & 63) * TSTRIDE + (idx >> 6)] = f32_to_bf16_rne(W[idx]);
    }
    __syncthreads();

    const int dst0 = blockIdx.x * 64 + wave * 16;
    if (dst0 >= n_dst) return;   // n_dst % 16 == 0: full 16-row waves only

    unsigned short* const strip = &ag[wave][0];

    // ---- Phase 1: aggregate 16 rows ----
    for (int r = 0; r < 16; ++r) {
        const int d = dst0 + r;
        const int cnt = counts[d];
        const int end = offsets[d];          // post-fill end
        const int beg = end - cnt;

        // self row x[d]
        float2 acc = *reinterpret_cast<const float2*>(&x[(size_t)d * IN_F + 2 * lane]);

        for (int base = beg; base < end; base += 64) {
            const int lim = min(64, end - base);
            const int sidx = (base + lane < end) ? elist[base + lane] : 0;
            int j = 0;
            for (; j + 4 <= lim; j += 4) {
                const int s0 = __shfl(sidx, j);
                const int s1 = __shfl(sidx, j + 1);
                const int s2 = __shfl(sidx, j + 2);
                const int s3 = __shfl(sidx, j + 3);
                const float2 v0 = *reinterpret_cast<const float2*>(&x[(size_t)s0 * IN_F + 2 * lane]);
                const float2 v1 = *reinterpret_cast<const float2*>(&x[(size_t)s1 * IN_F + 2 * lane]);
                const float2 v2 = *reinterpret_cast<const float2*>(&x[(size_t)s2 * IN_F + 2 * lane]);
                const float2 v3 = *reinterpret_cast<const float2*>(&x[(size_t)s3 * IN_F + 2 * lane]);
                acc.x += (v0.x + v1.x) + (v2.x + v3.x);
                acc.y += (v0.y + v1.y) + (v2.y + v3.y);
            }
            for (; j < lim; ++j) {
                const int s = __shfl(sidx, j);
                const float2 v = *reinterpret_cast<const float2*>(&x[(size_t)s * IN_F + 2 * lane]);
                acc.x += v.x;
                acc.y += v.y;
            }
        }

        // bf16-pack the two elements (cols 2*lane, 2*lane+1) -> one dword.
        const unsigned int packed = (unsigned int)f32_to_bf16_rne(acc.x)
                                  | ((unsigned int)f32_to_bf16_rne(acc.y) << 16);
        *reinterpret_cast<unsigned int*>(&strip[r * TSTRIDE + 2 * lane]) = packed;
    }

    // Same-wave LDS write->read ordering (rule #18).
    asm volatile("s_waitcnt lgkmcnt(0)" ::: "memory");
    __builtin_amdgcn_sched_barrier(0);

    // ---- Phase 2: 16x128 @ 128x64 MFMA + epilogue ----
    const int lrow = lane & 15;
    const int lkg  = lane >> 4;

    short8 a[4];
    #pragma unroll
    for (int s = 0; s < 4; ++s)
        a[s] = *reinterpret_cast<const short8*>(&strip[lrow * TSTRIDE + 32 * s + 8 * lkg]);

    floatx4 acc4[4];
    #pragma unroll
    for (int t = 0; t < 4; ++t) acc4[t] = (floatx4){0.f, 0.f, 0.f, 0.f};

    #pragma unroll
    for (int t = 0; t < 4; ++t)
        #pragma unroll
        for (int s = 0; s < 4; ++s) {
            const short8 bfr = *reinterpret_cast<const short8*>(
                &Wt[(16 * t + lrow) * TSTRIDE + 32 * s + 8 * lkg]);
            acc4[t] = __builtin_amdgcn_mfma_f32_16x16x32_bf16(a[s], bfr, acc4[t], 0, 0, 0);
        }

    // Epilogue: D row rr -> dst g = dst0 + 4*lkg + rr; col = 16*t + lrow.
    float bv[4];
    #pragma unroll
    for (int t = 0; t < 4; ++t) bv[t] = b[16 * t + lrow];

    #pragma unroll
    for (int rr = 0; rr < 4; ++rr) {
        const int g = dst0 + 4 * lkg + rr;
        const float inv = 1.0f / ((float)counts[g] + 1.0f);
        #pragma unroll
        for (int t = 0; t < 4; ++t)
            out[(size_t)g * OUT_F + 16 * t + lrow] = acc4[t][rr] * inv + bv[t];
    }
}

static inline size_t align256(size_t v) { return (v + 255) & ~(size_t)255; }

extern "C" void kernel_launch(void* const* d_in, const int* in_sizes, int n_in,
                              void* d_out, int out_size, void* d_ws, size_t ws_size,
                              hipStream_t stream) {
    const float* x    = (const float*)d_in[0];
    const int*   esrc = (const int*)d_in[1];
    const int*   edst = (const int*)d_in[2];
    const float* W    = (const float*)d_in[3];
    const float* b    = (const float*)d_in[4];

    const int n_edges = in_sizes[1];          // 800000
    const int n_dst   = out_size / OUT_F;     // 50000
    float* out = (float*)d_out;

    const int nScanBlocks = (n_dst + 255) / 256;            // 196

    // Workspace layout (tiny now: ~3.6 MB)
    const size_t cntOff = 0;
    const size_t offOff = align256(cntOff + (size_t)n_dst * 4);
    const size_t btOff  = align256(offOff + (size_t)n_dst * 4);
    const size_t bbOff  = align256(btOff + (size_t)nScanBlocks * 4);
    const size_t elOff  = align256(bbOff + (size_t)nScanBlocks * 4);
    const size_t needed = elOff + (size_t)n_edges * 4;

    if (ws_size >= needed) {
        int* counts      = (int*)((char*)d_ws + cntOff);
        int* offsets     = (int*)((char*)d_ws + offOff);
        int* blockTotals = (int*)((char*)d_ws + btOff);
        int* blockBases  = (int*)((char*)d_ws + bbOff);
        int* elist       = (int*)((char*)d_ws + elOff);

        hipMemsetAsync(counts, 0, (size_t)n_dst * 4, stream);

        const int eBlocks = (n_edges + 255) / 256;
        count_edges<<<eBlocks, 256, 0, stream>>>(edst, counts, n_edges);
        scan_blocks<<<nScanBlocks, 256, 0, stream>>>(counts, offsets, blockTotals, n_dst);
        scan_totals<<<1, 256, 0, stream>>>(blockTotals, blockBases, nScanBlocks);
        add_base<<<nScanBlocks, 256, 0, stream>>>(offsets, blockBases, n_dst);
        fill_edges<<<eBlocks, 256, 0, stream>>>(esrc, edst, offsets, elist, n_edges);

        const int gBlocks = (n_dst + 63) / 64;   // 782
        agg_gemm<<<gBlocks, 256, 0, stream>>>(x, W, offsets, counts, elist, b, out, n_dst);
    } else {
        hipMemsetAsync(out, 0, (size_t)out_size * sizeof(float), stream);
    }
}

// Round 10
// 144.436 us; speedup vs baseline: 1.2080x; 1.2080x over previous
//
#include <hip/hip_runtime.h>
#include <hip/hip_bf16.h>

#define IN_F   128
#define OUT_F  64
#define NC 256              // fused edge-count blocks appended to GEMM grid
#define TSTRIDE 136         // W^T LDS stride (ushorts)
#define OSTRIDE 136         // output-stage LDS stride (ushorts)

typedef __attribute__((ext_vector_type(8))) short short8;   // 8 bf16
typedef __attribute__((ext_vector_type(4))) float floatx4;  // MFMA accumulator

__device__ inline unsigned short f32_to_bf16_rne(float f) {
    unsigned int u = __float_as_uint(f);
    unsigned int r = (u + 0x7FFFu + ((u >> 16) & 1u)) >> 16;
    return (unsigned short)r;
}
__device__ inline float bf16_to_f32(unsigned short u) {
    return __uint_as_float((unsigned int)u << 16);
}

// ---------------------------------------------------------------------------
// K1 (fused): blocks [0,nTiles) = one 64-row GEMM tile each (h = x@W, bf16
// out); blocks [nTiles, nTiles+NC) = count_edges. NO persistent loop, NO
// register pipeline (r6-r8 lesson: compiler defeats it; VGPR stuck at 96
// with scratch spill). TLP instead: 12500 independent waves, ~90 VGPR,
// ~16 waves/CU. Per wave: 8 global float4 (own A rows) -> cvt -> 16 MFMA
// (B-frags ds_read per use) -> LDS transpose -> 2x16B contiguous stores.
// ---------------------------------------------------------------------------
__global__ __launch_bounds__(256) void gemm_count(const float* __restrict__ x,
                                                  const float* __restrict__ W,
                                                  unsigned short* __restrict__ h,
                                                  int nTiles,
                                                  const int* __restrict__ edst,
                                                  int* __restrict__ counts,
                                                  int n_edges) {
    __shared__ unsigned short Wt[64 * TSTRIDE];      // 17.4 KB
    __shared__ unsigned short ot[4][16 * OSTRIDE];   // 17.4 KB (per-wave strips)

    const int tid = threadIdx.x;

    if (blockIdx.x >= nTiles) {
        // --- count role ---
        const int stride = NC * 256;
        for (int e = (blockIdx.x - nTiles) * 256 + tid; e < n_edges; e += stride)
            atomicAdd(&counts[edst[e]], 1);
        return;
    }

    // --- GEMM role: one 64-row tile ---
    const int lane = tid & 63;
    const int wave = tid >> 6;          // 0..3 -> rows [16*wave, 16*wave+16)
    const int lrow = lane & 15;
    const int lkg  = lane >> 4;         // k-group; k offset = 8*lkg

    // W (128x64 f32) -> Wt[col][k] bf16 in LDS (L2-hit after first blocks).
    #pragma unroll
    for (int i = 0; i < 32; ++i) {
        const int idx = tid + i * 256;          // 0..8191
        Wt[(idx & 63) * TSTRIDE + (idx >> 6)] = f32_to_bf16_rne(W[idx]);
    }
    __syncthreads();

    const int tile = blockIdx.x;

    // Load this lane's A-fragment data: 8 float4 from its own x row.
    float4 xr[8];
    {
        const float* base = x + (size_t)tile * 64 * IN_F
                              + (size_t)(16 * wave + lrow) * IN_F + 8 * lkg;
        #pragma unroll
        for (int s = 0; s < 4; ++s) {
            xr[2 * s]     = *reinterpret_cast<const float4*>(base + 32 * s);
            xr[2 * s + 1] = *reinterpret_cast<const float4*>(base + 32 * s + 4);
        }
    }

    // Convert to bf16 A-fragments in-register.
    short8 a[4];
    #pragma unroll
    for (int s = 0; s < 4; ++s) {
        const float* f0 = reinterpret_cast<const float*>(&xr[2 * s]);
        const float* f1 = reinterpret_cast<const float*>(&xr[2 * s + 1]);
        short8 av;
        #pragma unroll
        for (int j = 0; j < 4; ++j) av[j] = (short)f32_to_bf16_rne(f0[j]);
        #pragma unroll
        for (int j = 0; j < 4; ++j) av[4 + j] = (short)f32_to_bf16_rne(f1[j]);
        a[s] = av;
    }

    // 16 MFMA; B-fragments read from LDS per use (saves 64 VGPRs vs hoist).
    floatx4 acc[4];
    #pragma unroll
    for (int t = 0; t < 4; ++t) acc[t] = (floatx4){0.f, 0.f, 0.f, 0.f};
    #pragma unroll
    for (int t = 0; t < 4; ++t)
        #pragma unroll
        for (int s = 0; s < 4; ++s) {
            const short8 bfr = *reinterpret_cast<const short8*>(
                &Wt[(16 * t + lrow) * TSTRIDE + 32 * s + 8 * lkg]);
            acc[t] = __builtin_amdgcn_mfma_f32_16x16x32_bf16(a[s], bfr, acc[t], 0, 0, 0);
        }

    // Stage D (bf16) into this wave's private LDS strip, transpose-read,
    // store 2x16B contiguous per lane. D: row=4*lkg+r, col=16*t+lrow.
    unsigned short* const op = &ot[wave][0];
    #pragma unroll
    for (int t = 0; t < 4; ++t)
        #pragma unroll
        for (int r = 0; r < 4; ++r)
            op[(4 * lkg + r) * OSTRIDE + 16 * t + lrow] = f32_to_bf16_rne(acc[t][r]);

    // Same-wave LDS write->read ordering (rule #18).
    asm volatile("s_waitcnt lgkmcnt(0)" ::: "memory");
    __builtin_amdgcn_sched_barrier(0);

    const int orow = lane >> 2;         // 0..15
    const int oseg = lane & 3;          // 0..3
    const short8 o0 = *reinterpret_cast<const short8*>(&op[orow * OSTRIDE + oseg * 16]);
    const short8 o1 = *reinterpret_cast<const short8*>(&op[orow * OSTRIDE + oseg * 16 + 8]);
    unsigned short* hb = h + ((size_t)tile * 64 + 16 * wave + orow) * OUT_F + oseg * 16;
    *reinterpret_cast<short8*>(hb) = o0;
    *reinterpret_cast<short8*>(hb + 8) = o1;
}

// ---------------------------------------------------------------------------
// Scan chain: per-block scan -> totals scan -> add base.
// ---------------------------------------------------------------------------
__global__ __launch_bounds__(256) void scan_blocks(const int* __restrict__ counts,
                                                   int* __restrict__ offsets,
                                                   int* __restrict__ blockTotals,
                                                   int n) {
    __shared__ int waveTot[4];
    const int tid = threadIdx.x;
    const int lane = tid & 63;
    const int wave = tid >> 6;
    const int i = blockIdx.x * 256 + tid;

    const int v = (i < n) ? counts[i] : 0;

    int s = v;
    #pragma unroll
    for (int off = 1; off < 64; off <<= 1) {
        const int t = __shfl_up(s, off, 64);
        if (lane >= off) s += t;
    }
    if (lane == 63) waveTot[wave] = s;
    __syncthreads();

    int base = 0;
    #pragma unroll
    for (int w = 0; w < 4; ++w)
        if (w < wave) base += waveTot[w];

    const int incl = s + base;
    if (i < n) offsets[i] = incl - v;
    if (tid == 255) blockTotals[blockIdx.x] = incl;
}

__global__ __launch_bounds__(256) void scan_totals(const int* __restrict__ blockTotals,
                                                   int* __restrict__ blockBases,
                                                   int nb) {
    __shared__ int part[256];
    const int t = threadIdx.x;
    const int v = (t < nb) ? blockTotals[t] : 0;
    part[t] = v;
    __syncthreads();
    for (int off = 1; off < 256; off <<= 1) {
        const int u = (t >= off) ? part[t - off] : 0;
        __syncthreads();
        part[t] += u;
        __syncthreads();
    }
    if (t < nb) blockBases[t] = part[t] - v;
}

__global__ __launch_bounds__(256) void add_base(int* __restrict__ offsets,
                                                const int* __restrict__ blockBases,
                                                int n) {
    const int i = blockIdx.x * 256 + threadIdx.x;
    if (i < n) offsets[i] += blockBases[blockIdx.x];
}

// fill bumps offsets (start -> end); gather recovers start via counts.
__global__ __launch_bounds__(256) void fill_edges(const int* __restrict__ esrc,
                                                  const int* __restrict__ edst,
                                                  int* __restrict__ offsets,
                                                  int* __restrict__ elist,
                                                  int n_edges) {
    const int e = blockIdx.x * 256 + threadIdx.x;
    if (e < n_edges) {
        const int d = edst[e];
        const int slot = atomicAdd(&offsets[d], 1);
        elist[slot] = esrc[e];
    }
}

// ---------------------------------------------------------------------------
// K5: gather + finalize (r8-proven). One wave per dst; 4 edges per load
// instruction (lane = 16*eq + p reads ushort4 of edge j+eq); fold across
// eq-groups via 2x __shfl_xor; 16 lanes write the float4 row.
// ---------------------------------------------------------------------------
__global__ __launch_bounds__(256) void gather_finalize(const unsigned short* __restrict__ h,
                                                       const int* __restrict__ offsets,
                                                       const int* __restrict__ counts,
                                                       const int* __restrict__ elist,
                                                       const float* __restrict__ b,
                                                       float* __restrict__ out,
                                                       int n_dst) {
    const int lane = threadIdx.x & 63;
    const int d = blockIdx.x * 4 + (threadIdx.x >> 6);
    if (d >= n_dst) return;

    const int eq = lane >> 4;           // edge slot 0..3
    const int p  = lane & 15;           // col group: cols [4p, 4p+4)

    const int cnt_d = counts[d];
    const int e1 = offsets[d];          // end (post-fill)
    const int e0 = e1 - cnt_d;

    float4 acc = {0.f, 0.f, 0.f, 0.f};

    for (int base = e0; base < e1; base += 64) {
        const int lim = min(64, e1 - base);
        const int sidx = (base + lane < e1) ? elist[base + lane] : 0;
        for (int j = 0; j < lim; j += 4) {
            const int myj = j + eq;
            const bool valid = myj < lim;
            const int s = __shfl(sidx, valid ? myj : 0);
            const ushort4 v = *reinterpret_cast<const ushort4*>(&h[(size_t)s * OUT_F + 4 * p]);
            const float w = valid ? 1.0f : 0.0f;
            acc.x += w * bf16_to_f32(v.x);
            acc.y += w * bf16_to_f32(v.y);
            acc.z += w * bf16_to_f32(v.z);
            acc.w += w * bf16_to_f32(v.w);
        }
    }

    acc.x += __shfl_xor(acc.x, 32); acc.y += __shfl_xor(acc.y, 32);
    acc.z += __shfl_xor(acc.z, 32); acc.w += __shfl_xor(acc.w, 32);
    acc.x += __shfl_xor(acc.x, 16); acc.y += __shfl_xor(acc.y, 16);
    acc.z += __shfl_xor(acc.z, 16); acc.w += __shfl_xor(acc.w, 16);

    if (lane < 16) {
        const ushort4 hd = *reinterpret_cast<const ushort4*>(&h[(size_t)d * OUT_F + 4 * p]);
        const float4 bb = *reinterpret_cast<const float4*>(&b[4 * p]);
        const float inv = 1.0f / ((float)cnt_d + 1.0f);
        float4 o;
        o.x = (acc.x + bf16_to_f32(hd.x)) * inv + bb.x;
        o.y = (acc.y + bf16_to_f32(hd.y)) * inv + bb.y;
        o.z = (acc.z + bf16_to_f32(hd.z)) * inv + bb.z;
        o.w = (acc.w + bf16_to_f32(hd.w)) * inv + bb.w;
        *reinterpret_cast<float4*>(&out[(size_t)d * OUT_F + 4 * p]) = o;
    }
}

static inline size_t align256(size_t v) { return (v + 255) & ~(size_t)255; }

extern "C" void kernel_launch(void* const* d_in, const int* in_sizes, int n_in,
                              void* d_out, int out_size, void* d_ws, size_t ws_size,
                              hipStream_t stream) {
    const float* x    = (const float*)d_in[0];
    const int*   esrc = (const int*)d_in[1];
    const int*   edst = (const int*)d_in[2];
    const float* W    = (const float*)d_in[3];
    const float* b    = (const float*)d_in[4];

    const int n_rows  = in_sizes[0] / IN_F;   // 200000
    const int n_edges = in_sizes[1];          // 800000
    const int n_dst   = out_size / OUT_F;     // 50000
    float* out = (float*)d_out;

    const int nScanBlocks = (n_dst + 255) / 256;            // 196

    // Workspace layout (h bf16: 25.6 MB)
    const size_t hBytes  = (size_t)n_rows * OUT_F * sizeof(unsigned short);
    const size_t cntOff  = align256(hBytes);
    const size_t offOff  = align256(cntOff + (size_t)n_dst * 4);
    const size_t btOff   = align256(offOff + (size_t)n_dst * 4);
    const size_t bbOff   = align256(btOff + (size_t)nScanBlocks * 4);
    const size_t elOff   = align256(bbOff + (size_t)nScanBlocks * 4);
    const size_t needed  = elOff + (size_t)n_edges * 4;

    unsigned short* h = (unsigned short*)d_ws;

    if (ws_size >= needed) {
        int* counts      = (int*)((char*)d_ws + cntOff);
        int* offsets     = (int*)((char*)d_ws + offOff);
        int* blockTotals = (int*)((char*)d_ws + btOff);
        int* blockBases  = (int*)((char*)d_ws + bbOff);
        int* elist       = (int*)((char*)d_ws + elOff);

        hipMemsetAsync(counts, 0, (size_t)n_dst * 4, stream);

        const int nTiles = n_rows / 64;       // 3125
        gemm_count<<<nTiles + NC, 256, 0, stream>>>(x, W, h, nTiles, edst, counts, n_edges);

        scan_blocks<<<nScanBlocks, 256, 0, stream>>>(counts, offsets, blockTotals, n_dst);
        scan_totals<<<1, 256, 0, stream>>>(blockTotals, blockBases, nScanBlocks);
        add_base<<<nScanBlocks, 256, 0, stream>>>(offsets, blockBases, n_dst);

        const int eBlocks = (n_edges + 255) / 256;
        fill_edges<<<eBlocks, 256, 0, stream>>>(esrc, edst, offsets, elist, n_edges);

        const int gBlocks = (n_dst + 3) / 4;
        gather_finalize<<<gBlocks, 256, 0, stream>>>(h, offsets, counts, elist, b, out, n_dst);
    } else {
        hipMemsetAsync(out, 0, (size_t)out_size * sizeof(float), stream);
    }
}

// Round 11
// 137.516 us; speedup vs baseline: 1.2688x; 1.0503x over previous
//
#include <hip/hip_runtime.h>
#include <hip/hip_bf16.h>

#define IN_F   128
#define OUT_F  64
#define NG 768              // persistent GEMM blocks (3/CU)
#define NC 256              // edge-count blocks (1/CU); NG+NC = 1024 = 4/CU
#define TSTRIDE 136         // W^T LDS stride (ushorts, 16B-aligned rows)
#define OSTRIDE 136         // output-stage LDS stride

typedef __attribute__((ext_vector_type(8))) short short8;   // 8 bf16
typedef __attribute__((ext_vector_type(4))) float floatx4;  // MFMA accumulator

__device__ inline unsigned short f32_to_bf16_rne(float f) {
    unsigned int u = __float_as_uint(f);
    unsigned int r = (u + 0x7FFFu + ((u >> 16) & 1u)) >> 16;
    return (unsigned short)r;
}
__device__ inline float bf16_to_f32(unsigned short u) {
    return __uint_as_float((unsigned int)u << 16);
}
// 2x f32 -> packed bf16 dword (RNE), single instruction.
__device__ inline unsigned int cvt_pk_bf16(float lo, float hi) {
    unsigned int r;
    asm volatile("v_cvt_pk_bf16_f32 %0, %1, %2" : "=v"(r) : "v"(lo), "v"(hi));
    return r;
}

// ---------------------------------------------------------------------------
// K1 (fused): blocks [0,NG) = persistent GEMM (h = x@W, bf16 out), blocks
// [NG,NG+NC) = count_edges. 4 blocks/CU co-resident; W setup amortized over
// ~4 tiles/block; NO in-loop barriers (Wt read-only, per-wave ot strips);
// NO register pipeline (r8 lesson: compiler defeats it; TLP hides latency).
// ---------------------------------------------------------------------------
__global__ __launch_bounds__(256) void gemm_count(const float* __restrict__ x,
                                                  const float* __restrict__ W,
                                                  unsigned short* __restrict__ h,
                                                  int nTiles,
                                                  const int* __restrict__ edst,
                                                  int* __restrict__ counts,
                                                  int n_edges) {
    __shared__ unsigned short Wt[64 * TSTRIDE];      // 17.4 KB
    __shared__ unsigned short ot[4][16 * OSTRIDE];   // 17.4 KB (per-wave strips)

    const int tid = threadIdx.x;

    if (blockIdx.x >= NG) {
        // --- count role ---
        const int stride = NC * 256;
        for (int e = (blockIdx.x - NG) * 256 + tid; e < n_edges; e += stride)
            atomicAdd(&counts[edst[e]], 1);
        return;
    }

    // --- GEMM role ---
    const int lane = tid & 63;
    const int wave = tid >> 6;          // 0..3 -> rows [16*wave, 16*wave+16)
    const int lrow = lane & 15;
    const int lkg  = lane >> 4;         // k-group; k offset = 8*lkg

    // One-time W (128x64 f32) -> Wt[col][k] bf16.
    #pragma unroll
    for (int i = 0; i < 32; ++i) {
        const int idx = tid + i * 256;          // 0..8191
        Wt[(idx & 63) * TSTRIDE + (idx >> 6)] = f32_to_bf16_rne(W[idx]);
    }
    __syncthreads();

    unsigned short* const op = &ot[wave][0];
    const int orow = lane >> 2;         // 0..15 (readback row)
    const int oseg = lane & 3;          // 0..3  (32B segment)

    for (int tile = blockIdx.x; tile < nTiles; tile += NG) {
        // Load this lane's A rows: 8 float4 from its own x row.
        float4 xr[8];
        {
            const float* base = x + (size_t)tile * 64 * IN_F
                                  + (size_t)(16 * wave + lrow) * IN_F + 8 * lkg;
            #pragma unroll
            for (int s = 0; s < 4; ++s) {
                xr[2 * s]     = *reinterpret_cast<const float4*>(base + 32 * s);
                xr[2 * s + 1] = *reinterpret_cast<const float4*>(base + 32 * s + 4);
            }
        }

        // f32 -> bf16 A-fragments via v_cvt_pk (4 instr per fragment).
        short8 a[4];
        #pragma unroll
        for (int s = 0; s < 4; ++s) {
            const float* f0 = reinterpret_cast<const float*>(&xr[2 * s]);
            const float* f1 = reinterpret_cast<const float*>(&xr[2 * s + 1]);
            union { unsigned int u[4]; short8 v; } cv;
            cv.u[0] = cvt_pk_bf16(f0[0], f0[1]);
            cv.u[1] = cvt_pk_bf16(f0[2], f0[3]);
            cv.u[2] = cvt_pk_bf16(f1[0], f1[1]);
            cv.u[3] = cvt_pk_bf16(f1[2], f1[3]);
            a[s] = cv.v;
        }

        // 16 MFMA; B-fragments read from LDS per use.
        floatx4 acc[4];
        #pragma unroll
        for (int t = 0; t < 4; ++t) acc[t] = (floatx4){0.f, 0.f, 0.f, 0.f};
        #pragma unroll
        for (int t = 0; t < 4; ++t)
            #pragma unroll
            for (int s = 0; s < 4; ++s) {
                const short8 bfr = *reinterpret_cast<const short8*>(
                    &Wt[(16 * t + lrow) * TSTRIDE + 32 * s + 8 * lkg]);
                acc[t] = __builtin_amdgcn_mfma_f32_16x16x32_bf16(a[s], bfr, acc[t], 0, 0, 0);
            }

        // Stage D (bf16) in this wave's strip; D: row=4*lkg+r, col=16*t+lrow.
        #pragma unroll
        for (int t = 0; t < 4; ++t)
            #pragma unroll
            for (int r = 0; r < 4; ++r)
                op[(4 * lkg + r) * OSTRIDE + 16 * t + lrow] = f32_to_bf16_rne(acc[t][r]);

        // Same-wave LDS write->read ordering (rule #18).
        asm volatile("s_waitcnt lgkmcnt(0)" ::: "memory");
        __builtin_amdgcn_sched_barrier(0);

        // Transpose-read; each lane stores 32 contiguous bytes.
        const short8 o0 = *reinterpret_cast<const short8*>(&op[orow * OSTRIDE + oseg * 16]);
        const short8 o1 = *reinterpret_cast<const short8*>(&op[orow * OSTRIDE + oseg * 16 + 8]);
        unsigned short* hb = h + ((size_t)tile * 64 + 16 * wave + orow) * OUT_F + oseg * 16;
        *reinterpret_cast<short8*>(hb) = o0;
        *reinterpret_cast<short8*>(hb + 8) = o1;
    }
}

// ---------------------------------------------------------------------------
// Scan chain: per-block scan -> totals scan -> add base.
// ---------------------------------------------------------------------------
__global__ __launch_bounds__(256) void scan_blocks(const int* __restrict__ counts,
                                                   int* __restrict__ offsets,
                                                   int* __restrict__ blockTotals,
                                                   int n) {
    __shared__ int waveTot[4];
    const int tid = threadIdx.x;
    const int lane = tid & 63;
    const int wave = tid >> 6;
    const int i = blockIdx.x * 256 + tid;

    const int v = (i < n) ? counts[i] : 0;

    int s = v;
    #pragma unroll
    for (int off = 1; off < 64; off <<= 1) {
        const int t = __shfl_up(s, off, 64);
        if (lane >= off) s += t;
    }
    if (lane == 63) waveTot[wave] = s;
    __syncthreads();

    int base = 0;
    #pragma unroll
    for (int w = 0; w < 4; ++w)
        if (w < wave) base += waveTot[w];

    const int incl = s + base;
    if (i < n) offsets[i] = incl - v;
    if (tid == 255) blockTotals[blockIdx.x] = incl;
}

__global__ __launch_bounds__(256) void scan_totals(const int* __restrict__ blockTotals,
                                                   int* __restrict__ blockBases,
                                                   int nb) {
    __shared__ int part[256];
    const int t = threadIdx.x;
    const int v = (t < nb) ? blockTotals[t] : 0;
    part[t] = v;
    __syncthreads();
    for (int off = 1; off < 256; off <<= 1) {
        const int u = (t >= off) ? part[t - off] : 0;
        __syncthreads();
        part[t] += u;
        __syncthreads();
    }
    if (t < nb) blockBases[t] = part[t] - v;
}

__global__ __launch_bounds__(256) void add_base(int* __restrict__ offsets,
                                                const int* __restrict__ blockBases,
                                                int n) {
    const int i = blockIdx.x * 256 + threadIdx.x;
    if (i < n) offsets[i] += blockBases[blockIdx.x];
}

// fill bumps offsets (start -> end); gather recovers start via counts.
__global__ __launch_bounds__(256) void fill_edges(const int* __restrict__ esrc,
                                                  const int* __restrict__ edst,
                                                  int* __restrict__ offsets,
                                                  int* __restrict__ elist,
                                                  int n_edges) {
    const int e = blockIdx.x * 256 + threadIdx.x;
    if (e < n_edges) {
        const int d = edst[e];
        const int slot = atomicAdd(&offsets[d], 1);
        elist[slot] = esrc[e];
    }
}

// ---------------------------------------------------------------------------
// K5: gather + finalize (r8-proven). One wave per dst; 4 edges per load
// instruction; fold across eq-groups via 2x __shfl_xor.
// ---------------------------------------------------------------------------
__global__ __launch_bounds__(256) void gather_finalize(const unsigned short* __restrict__ h,
                                                       const int* __restrict__ offsets,
                                                       const int* __restrict__ counts,
                                                       const int* __restrict__ elist,
                                                       const float* __restrict__ b,
                                                       float* __restrict__ out,
                                                       int n_dst) {
    const int lane = threadIdx.x & 63;
    const int d = blockIdx.x * 4 + (threadIdx.x >> 6);
    if (d >= n_dst) return;

    const int eq = lane >> 4;           // edge slot 0..3
    const int p  = lane & 15;           // col group: cols [4p, 4p+4)

    const int cnt_d = counts[d];
    const int e1 = offsets[d];          // end (post-fill)
    const int e0 = e1 - cnt_d;

    float4 acc = {0.f, 0.f, 0.f, 0.f};

    for (int base = e0; base < e1; base += 64) {
        const int lim = min(64, e1 - base);
        const int sidx = (base + lane < e1) ? elist[base + lane] : 0;
        for (int j = 0; j < lim; j += 4) {
            const int myj = j + eq;
            const bool valid = myj < lim;
            const int s = __shfl(sidx, valid ? myj : 0);
            const ushort4 v = *reinterpret_cast<const ushort4*>(&h[(size_t)s * OUT_F + 4 * p]);
            const float w = valid ? 1.0f : 0.0f;
            acc.x += w * bf16_to_f32(v.x);
            acc.y += w * bf16_to_f32(v.y);
            acc.z += w * bf16_to_f32(v.z);
            acc.w += w * bf16_to_f32(v.w);
        }
    }

    acc.x += __shfl_xor(acc.x, 32); acc.y += __shfl_xor(acc.y, 32);
    acc.z += __shfl_xor(acc.z, 32); acc.w += __shfl_xor(acc.w, 32);
    acc.x += __shfl_xor(acc.x, 16); acc.y += __shfl_xor(acc.y, 16);
    acc.z += __shfl_xor(acc.z, 16); acc.w += __shfl_xor(acc.w, 16);

    if (lane < 16) {
        const ushort4 hd = *reinterpret_cast<const ushort4*>(&h[(size_t)d * OUT_F + 4 * p]);
        const float4 bb = *reinterpret_cast<const float4*>(&b[4 * p]);
        const float inv = 1.0f / ((float)cnt_d + 1.0f);
        float4 o;
        o.x = (acc.x + bf16_to_f32(hd.x)) * inv + bb.x;
        o.y = (acc.y + bf16_to_f32(hd.y)) * inv + bb.y;
        o.z = (acc.z + bf16_to_f32(hd.z)) * inv + bb.z;
        o.w = (acc.w + bf16_to_f32(hd.w)) * inv + bb.w;
        *reinterpret_cast<float4*>(&out[(size_t)d * OUT_F + 4 * p]) = o;
    }
}

static inline size_t align256(size_t v) { return (v + 255) & ~(size_t)255; }

extern "C" void kernel_launch(void* const* d_in, const int* in_sizes, int n_in,
                              void* d_out, int out_size, void* d_ws, size_t ws_size,
                              hipStream_t stream) {
    const float* x    = (const float*)d_in[0];
    const int*   esrc = (const int*)d_in[1];
    const int*   edst = (const int*)d_in[2];
    const float* W    = (const float*)d_in[3];
    const float* b    = (const float*)d_in[4];

    const int n_rows  = in_sizes[0] / IN_F;   // 200000
    const int n_edges = in_sizes[1];          // 800000
    const int n_dst   = out_size / OUT_F;     // 50000
    float* out = (float*)d_out;

    const int nScanBlocks = (n_dst + 255) / 256;            // 196

    // Workspace layout (h bf16: 25.6 MB)
    const size_t hBytes  = (size_t)n_rows * OUT_F * sizeof(unsigned short);
    const size_t cntOff  = align256(hBytes);
    const size_t offOff  = align256(cntOff + (size_t)n_dst * 4);
    const size_t btOff   = align256(offOff + (size_t)n_dst * 4);
    const size_t bbOff   = align256(btOff + (size_t)nScanBlocks * 4);
    const size_t elOff   = align256(bbOff + (size_t)nScanBlocks * 4);
    const size_t needed  = elOff + (size_t)n_edges * 4;

    unsigned short* h = (unsigned short*)d_ws;

    if (ws_size >= needed) {
        int* counts      = (int*)((char*)d_ws + cntOff);
        int* offsets     = (int*)((char*)d_ws + offOff);
        int* blockTotals = (int*)((char*)d_ws + btOff);
        int* blockBases  = (int*)((char*)d_ws + bbOff);
        int* elist       = (int*)((char*)d_ws + elOff);

        hipMemsetAsync(counts, 0, (size_t)n_dst * 4, stream);

        const int nTiles = n_rows / 64;       // 3125
        gemm_count<<<NG + NC, 256, 0, stream>>>(x, W, h, nTiles, edst, counts, n_edges);

        scan_blocks<<<nScanBlocks, 256, 0, stream>>>(counts, offsets, blockTotals, n_dst);
        scan_totals<<<1, 256, 0, stream>>>(blockTotals, blockBases, nScanBlocks);
        add_base<<<nScanBlocks, 256, 0, stream>>>(offsets, blockBases, n_dst);

        const int eBlocks = (n_edges + 255) / 256;
        fill_edges<<<eBlocks, 256, 0, stream>>>(esrc, edst, offsets, elist, n_edges);

        const int gBlocks = (n_dst + 3) / 4;
        gather_finalize<<<gBlocks, 256, 0, stream>>>(h, offsets, counts, elist, b, out, n_dst);
    } else {
        hipMemsetAsync(out, 0, (size_t)out_size * sizeof(float), stream);
    }
}